// Round 12
// baseline (344.681 us; speedup 1.0000x reference)
//
#include <hip/hip_runtime.h>
#include <stdint.h>

typedef short short8 __attribute__((ext_vector_type(8)));
typedef float f32x4 __attribute__((ext_vector_type(4)));

#define NPB     100    // n-rows per block; 1000 blocks * 100 = 100000 exactly
#define NPH     50     // row PAIRS per block
#define NBLOCKS 1000

__device__ __forceinline__ uint32_t f32_to_bf16_rne(float f) {
    uint32_t u = __builtin_bit_cast(uint32_t, f);
    uint32_t r = u + 0x7FFFu + ((u >> 16) & 1u);
    return r >> 16;
}
// packed f32x2 -> bf16x2 (RNE), single VALU op
__device__ __forceinline__ uint32_t cvt_pk_bf16(float lo, float hi) {
    uint32_t r;
    asm("v_cvt_pk_bf16_f32 %0, %1, %2" : "=v"(r) : "v"(lo), "v"(hi));
    return r;
}

// async global->LDS, 16B per lane; LDS dest = wave-uniform base + lane*16
#define GLOAD_LDS16(g, l)                                                  \
    __builtin_amdgcn_global_load_lds(                                      \
        (const __attribute__((address_space(1))) void*)(g),                \
        (__attribute__((address_space(3))) void*)(l), 16, 0, 0)

// ---------------------------------------------------------------------------
// Pre-kernel: Wt[l][o][i] = bf16(w_l[i][o])  (transposed so A-fragments are
// contiguous-in-i 16B loads). 4 * 128 * 128 bf16 = 128 KB in d_ws.
// ---------------------------------------------------------------------------
__global__ void conv_weights(const float* __restrict__ w0, const float* __restrict__ w1,
                             const float* __restrict__ w2, const float* __restrict__ w3,
                             uint16_t* __restrict__ wt) {
    int idx = blockIdx.x * 256 + threadIdx.x;   // 0 .. 65535
    int l = idx >> 14;
    int o = (idx >> 7) & 127;
    int i = idx & 127;
    const float* w = (l == 0) ? w0 : (l == 1) ? w1 : (l == 2) ? w2 : w3;
    wt[idx] = (uint16_t)f32_to_bf16_rne(w[i * 128 + o]);
}

// ---------------------------------------------------------------------------
// Main kernel, ROUND 12: row-PAIR phases, 2 o-tiles per wave.
// r11 audit: swizzle null -> LDS b32 *instruction throughput* (256 instr/row
// x 5.8cy = 1485cy) ~ HBM (1560cy) and they overlap imperfectly (measured
// 2060cy/row). B-fragments (x) are identical across waves; amortize each
// over TWO A-tiles: waves 0-3 compute row 2p (o-group (wid&3)*32, two
// 16-tiles), waves 4-7 compute row 2p+1. LDS reads/row: 256 -> 128 instr
// (~740cy) -> HBM becomes binding.
//
// Ring: 4 slots x 16 KB (row pair), 3 phases ahead. Counted vmcnt, never
// drained in steady state: per phase each thread issues 2 gload_lds + 8
// stores; ops younger than load-pair(p) = 8+2+8+2+8 = 28 -> vmcnt(28);
// tail (p>=48): 24. Prologue drains once (vmcnt(0)) so counts are invariant.
//
// LDS layout per row (unchanged, r11-verified): idx(i,c)=(i^((i>>3)&1))*16+c
// via pre-swizzled source granule srcg = tid ^ (((tid>>5)&1)<<2); read
// rowp[((i)^ (kg&1))*16 + c] returns x[i][c] in ascending-i order.
//
// Compute: A = wfr[2][4][4] (two o-tiles, register/AGPR-resident),
// B = x from LDS (32 b32 reads + 16 cvt_pk per wave per phase), 4 unmasked
// l-passes into acc[tile][l], per-lane l(c)-select at store.
// MFMA 16x16x32 bf16 (m89-verified): A row=lane&15(=o_loc), k=(lane>>4)*8+j;
// B col=lane&15(=c); D col=lane&15(=c), row=(lane>>4)*4+reg(=o_loc).
// ---------------------------------------------------------------------------
__global__ void __launch_bounds__(512, 1)
isl_kernel(const float* __restrict__ x,
           const uint16_t* __restrict__ wt,
           float* __restrict__ out) {
    __shared__ uint8_t ldsbuf[4][16384];
    const int tid   = threadIdx.x;
    const int lane  = tid & 63;
    const int wid   = tid >> 6;      // 0..7
    const int rhalf = wid >> 2;      // which row of the pair this wave computes
    const int og    = (wid & 3) * 32; // 32-wide o-group (two 16-tiles)
    const int r16   = lane & 15;     // A-row (o_loc) / B-col & D-col (c)
    const int kg    = lane >> 4;     // 0..3
    const int kx1   = kg & 1;        // read-side swizzle bit

    // ---- weight fragments: two o-tiles, resident for the whole block
    short8 wfr[2][4][4];             // [tile][l][ks]
    #pragma unroll
    for (int t = 0; t < 2; ++t) {
        const uint16_t* wb = wt + (size_t)(og + t * 16 + r16) * 128 + kg * 8;
        #pragma unroll
        for (int l = 0; l < 4; ++l)
            #pragma unroll
            for (int ks = 0; ks < 4; ++ks)
                wfr[t][l][ks] = *(const short8*)(wb + l * 16384 + ks * 32);
    }

    const int n0 = blockIdx.x * NPB;
    // per-thread global src granule, pre-swizzled (involution, 16B granules)
    const int srcg = tid ^ (((tid >> 5) & 1) << 2);
    const uint8_t* xg = (const uint8_t*)(x + (size_t)n0 * 2048) + (size_t)srcg * 16;

    // ---- prologue: stage phases 0..2 (rows 0..5), drain once, sync
    #pragma unroll
    for (int p = 0; p < 3; ++p)
        #pragma unroll
        for (int h = 0; h < 2; ++h)
            GLOAD_LDS16(xg + (size_t)(2 * p + h) * 8192,
                        &ldsbuf[p][h * 8192 + wid * 1024]);
    asm volatile("s_waitcnt vmcnt(0)" ::: "memory");
    __builtin_amdgcn_s_barrier();

    // per-thread out base for this wave's row-half and o-group
    float* po_base = out + (size_t)(n0 + rhalf) * 2048 +
                     (size_t)(og + kg * 4) * 16 + r16;

    #pragma unroll 1
    for (int p = 0; p < NPH; ++p) {
        if (p > 0) {
            if (p <= NPH - 3)
                asm volatile("s_waitcnt vmcnt(28)" ::: "memory");
            else
                asm volatile("s_waitcnt vmcnt(24)" ::: "memory");
            __builtin_amdgcn_s_barrier();
        }
        // ---- prefetch phase p+3 (slot (p+3)&3 = (p-1)&3, free after barrier)
        if (p + 3 < NPH) {
            GLOAD_LDS16(xg + (size_t)(2 * (p + 3)) * 8192,
                        &ldsbuf[(p + 3) & 3][wid * 1024]);
            GLOAD_LDS16(xg + (size_t)(2 * (p + 3) + 1) * 8192,
                        &ldsbuf[(p + 3) & 3][8192 + wid * 1024]);
        }

        // ---- B fragments from this wave's row half (swizzled read: i ^= kg&1)
        const float* rowp = (const float*)&ldsbuf[p & 3][rhalf * 8192];
        short8 xb[4];
        #pragma unroll
        for (int ks = 0; ks < 4; ++ks) {
            float f[8];
            #pragma unroll
            for (int j = 0; j < 8; ++j)
                f[j] = rowp[((ks * 32 + kg * 8 + j) ^ kx1) * 16 + r16];
            uint32_t q[4];
            #pragma unroll
            for (int h = 0; h < 4; ++h)
                q[h] = cvt_pk_bf16(f[2 * h], f[2 * h + 1]);
            xb[ks] = *(const short8*)q;
        }

        // ---- 2 o-tiles x 4 l-passes, B shared
        f32x4 acc[2][4];
        #pragma unroll
        for (int t = 0; t < 2; ++t)
            #pragma unroll
            for (int l = 0; l < 4; ++l)
                acc[t][l] = (f32x4){0.f, 0.f, 0.f, 0.f};
        #pragma unroll
        for (int t = 0; t < 2; ++t)
            #pragma unroll
            for (int l = 0; l < 4; ++l)
                #pragma unroll
                for (int ks = 0; ks < 4; ++ks)
                    acc[t][l] = __builtin_amdgcn_mfma_f32_16x16x32_bf16(
                        wfr[t][l][ks], xb[ks], acc[t][l], 0, 0, 0);

        // ---- store: row = 2p + rhalf; per tile 4 dwords, per-lane l(c)-select
        float* po = po_base + (size_t)(2 * p) * 2048;
        #pragma unroll
        for (int t = 0; t < 2; ++t) {
            #pragma unroll
            for (int rr = 0; rr < 4; ++rr) {
                float v = acc[t][0][rr];
                v = (r16 >= 1) ? acc[t][1][rr] : v;
                v = (r16 >= 4) ? acc[t][2][rr] : v;
                v = (r16 >= 9) ? acc[t][3][rr] : v;
                po[(t * 16 + rr) * 16] = v;
            }
        }
    }
}

extern "C" void kernel_launch(void* const* d_in, const int* in_sizes, int n_in,
                              void* d_out, int out_size, void* d_ws, size_t ws_size,
                              hipStream_t stream) {
    const float* x  = (const float*)d_in[0];
    const float* w0 = (const float*)d_in[1];
    const float* w1 = (const float*)d_in[2];
    const float* w2 = (const float*)d_in[3];
    const float* w3 = (const float*)d_in[4];
    uint16_t* wt = (uint16_t*)d_ws;          // 128 KB scratch
    float* out = (float*)d_out;

    conv_weights<<<256, 256, 0, stream>>>(w0, w1, w2, w3, wt);
    isl_kernel<<<NBLOCKS, 512, 0, stream>>>(x, wt, out);
}